// Round 2
// baseline (2132.657 us; speedup 1.0000x reference)
//
#include <hip/hip_runtime.h>
#include <hip/hip_bf16.h>

// PCFG inside algorithm, B=16, n=32, NT=30, T=60, S=90.
// score[b,s,w,a] = log sum_{u,x,c} exp(left[u,x] + right[u,c] + rule[a,x,c])
// computed as  S[a] = sum_{x,c} H[x,c] * er[a,x,c],  H[x,c] = sum_u A'[u,x]*Bv[u,c]
// with A'[u,x] = exp(l + mr_u - K), Bv[u,c] = exp(r - mr_u),
// K = max_u (rowmax(left_u) + rowmax(right_u)); score = log(S) + K.

#define Bn   16
#define Nn   32
#define Tt   60
#define NTn  30
#define Sn   90
#define SPn  96
#define NEGF (-1.0e9f)

// ws layout (floats)
#define ER_OFF   0                         // exp(rule): [16][30][8100]
#define BETA_OFF 3888000                   // beta: [16][32][32][96]
#define RM_OFF   (BETA_OFF + 16*32*32*96)  // rowmax: [16][32][32]
#define SA_OFF   (RM_OFF + 16*32*32)       // S accumulators, per-width regions
#define SA_TOTAL 238080                    // sum_w 16*(32-w)*30

__global__ void k_exp(const float* __restrict__ rule, float* __restrict__ er, int n) {
  int i = blockIdx.x * 256 + threadIdx.x;
  if (i < n) er[i] = __expf(rule[i]);
}

__global__ void k_init(const float* __restrict__ unary, float* __restrict__ ws) {
  int i = blockIdx.x * 256 + threadIdx.x;
  float* beta   = ws + BETA_OFF;
  float* rowmax = ws + RM_OFF;
  float* Sacc   = ws + SA_OFF;
  if (i < 16*32*32*96) {
    int c = i % SPn; int r = i / SPn;
    int j = r % Nn; r /= Nn;
    int ii = r % Nn; int b = r / Nn;
    float v = NEGF;
    if (ii == j && c >= NTn && c < Sn) v = unary[(b*Nn + ii)*Tt + (c - NTn)];
    beta[i] = v;
  }
  if (i < 16*32*32) {
    int j = i % Nn; int r = i / Nn;
    int ii = r % Nn; int b = r / Nn;
    float m = NEGF;
    if (ii == j) {
      const float* u = unary + (b*Nn + ii)*Tt;
      for (int t = 0; t < Tt; ++t) m = fmaxf(m, u[t]);
    }
    rowmax[i] = m;
  }
  if (i < SA_TOTAL) Sacc[i] = 0.0f;
}

__global__ __launch_bounds__(256) void k_step(float* __restrict__ ws, int w,
                                              int baseCur, int basePrev) {
  const int chunk = blockIdx.x;            // 0..14, x-range [6*chunk, 6*chunk+6)
  const int b     = blockIdx.y;            // 0..15
  const int tid   = threadIdx.x;
  const int ns    = Nn - w;
  const int x0    = chunk * 6;
  const int u_lo  = (x0 >= NTn) ? 0 : 1;   // x>=NT only left-diag (u=0); x<NT only u>=1
  const int u_hi  = (x0 >= NTn) ? 1 : w;
  const int nu    = u_hi - u_lo;

  const float* er = ws + ER_OFF;
  float* beta   = ws + BETA_OFF;
  float* rowmax = ws + RM_OFF;
  float* Sacc   = ws + SA_OFF;

  float* betaB = beta + (size_t)b * Nn * Nn * SPn;
  float* rmB   = rowmax + b * Nn * Nn;

  __shared__ float finrow[31][NTn];
  __shared__ float finmax[32];
  __shared__ float KW[32];
  __shared__ float Aa[30][8];
  __shared__ float Bv[30][Sn];
  __shared__ __align__(16) float Hh[540];

  // ---- exp(rule) slice into registers, issued EARLY so the L2/L3 latency
  // overlaps the finalize phase below (er is read-only after k_exp).
  // Thread owns 4 a-values x 5 float4 of k.
  const int g = tid >> 5;   // a-group 0..7
  const int j = tid & 31;   // k-lane 0..31
  float4 ereg[4][5];
  int    avals[4];
  #pragma unroll
  for (int m = 0; m < 4; ++m) {
    int a = g + 8*m;
    avals[m] = (a < NTn) ? a : -1;
    const float4* Ev = (const float4*)(er + ((size_t)b*NTn + (a < NTn ? a : 0))*8100 + x0*Sn);
    #pragma unroll
    for (int i = 0; i < 5; ++i) {
      int f = j + 32*i;
      float4 v = make_float4(0.f, 0.f, 0.f, 0.f);
      if (a < NTn && f < 135) v = Ev[f];
      ereg[m][i] = v;
    }
  }

  // ---- finalize width w-1 rows (redundant per block; bitwise-identical writes) ----
  if (w >= 2) {
    const int wp = w - 1, nsp = Nn - wp;
    if (tid < nsp) {
      float K = -3.0e38f;
      for (int u = 0; u < wp; ++u)
        K = fmaxf(K, rmB[tid*Nn + (tid+u)] + rmB[(tid+u+1)*Nn + (tid+wp)]);
      KW[tid] = K;
    }
    __syncthreads();
    for (int t = tid; t < nsp*NTn; t += 256) {
      int sp = t / NTn, a = t - sp*NTn;
      float sv = Sacc[basePrev + (b*nsp + sp)*NTn + a];
      float sc = __logf(fmaxf(sv, 1e-38f)) + KW[sp];
      finrow[sp][a] = sc;
      betaB[(sp*Nn + (sp+wp))*SPn + a] = sc;
    }
    __syncthreads();
    if (tid < nsp) {
      float m = -3.0e38f;
      for (int a = 0; a < NTn; ++a) m = fmaxf(m, finrow[tid][a]);
      finmax[tid] = m;
      rmB[tid*Nn + (tid+wp)] = m;
    }
    __syncthreads();
  }

  if (nu <= 0) return;   // only happens at w==1 for x<NT chunks (block-uniform)

  // ---- K stabilizers for current width ----
  if (tid < ns) {
    float K = -3.0e38f;
    for (int u = 0; u < w; ++u) {
      float rl = (w >= 2 && u == w-1) ? finmax[tid]   : rmB[tid*Nn + (tid+u)];
      float rr = (w >= 2 && u == 0)   ? finmax[tid+1] : rmB[(tid+u+1)*Nn + (tid+w)];
      K = fmaxf(K, rl + rr);
    }
    KW[tid] = K;
  }
  __syncthreads();

  // ---- span loop ----
  for (int s = 0; s < ns; ++s) {
    const float K = KW[s];
    // A'[r][xi] = exp(l + mr_u - K)
    for (int t = tid; t < nu*6; t += 256) {
      int r = t / 6, xi = t - r*6;
      int u = u_lo + r;
      int x = x0 + xi;
      float l;
      if (w >= 2 && u == w-1) l = (x < NTn) ? finrow[s][x] : NEGF;
      else                    l = betaB[(s*Nn + (s+u))*SPn + x];
      float rr = (w >= 2 && u == 0) ? finmax[s+1] : rmB[(s+u+1)*Nn + (s+w)];
      Aa[r][xi] = __expf(l + rr - K);
    }
    // Bv[r][c] = exp(r - mr_u)
    for (int t = tid; t < nu*Sn; t += 256) {
      int r = t / Sn, c = t - r*Sn;
      int u = u_lo + r;
      float v;
      if (w >= 2 && u == 0) v = (c < NTn) ? finrow[s+1][c] : NEGF;
      else                  v = betaB[((s+u+1)*Nn + (s+w))*SPn + c];
      float rr = (w >= 2 && u == 0) ? finmax[s+1] : rmB[(s+u+1)*Nn + (s+w)];
      Bv[r][c] = __expf(v - rr);
    }
    __syncthreads();
    // H[x'][c] = sum_u A'*Bv
    for (int t = tid; t < 540; t += 256) {
      int xi = t / Sn, c = t - xi*Sn;
      float acc = 0.f;
      for (int r = 0; r < nu; ++r) acc = fmaf(Aa[r][xi], Bv[r][c], acc);
      Hh[t] = acc;
    }
    __syncthreads();
    // dots: S[a] partial = sum_k H[k]*er[a][k], split-K atomics
    {
      const float4* Hv = (const float4*)Hh;
      float acc0 = 0.f, acc1 = 0.f, acc2 = 0.f, acc3 = 0.f;
      #pragma unroll
      for (int i = 0; i < 5; ++i) {
        int f = j + 32*i;
        if (f < 135) {
          float4 h = Hv[f];
          acc0 += h.x*ereg[0][i].x + h.y*ereg[0][i].y + h.z*ereg[0][i].z + h.w*ereg[0][i].w;
          acc1 += h.x*ereg[1][i].x + h.y*ereg[1][i].y + h.z*ereg[1][i].z + h.w*ereg[1][i].w;
          acc2 += h.x*ereg[2][i].x + h.y*ereg[2][i].y + h.z*ereg[2][i].z + h.w*ereg[2][i].w;
          acc3 += h.x*ereg[3][i].x + h.y*ereg[3][i].y + h.z*ereg[3][i].z + h.w*ereg[3][i].w;
        }
      }
      #pragma unroll
      for (int d = 16; d >= 1; d >>= 1) {
        acc0 += __shfl_down(acc0, d, 32);
        acc1 += __shfl_down(acc1, d, 32);
        acc2 += __shfl_down(acc2, d, 32);
        acc3 += __shfl_down(acc3, d, 32);
      }
      if (j == 0) {
        float* Sp = Sacc + baseCur + (b*ns + s)*NTn;
        if (avals[0] >= 0) atomicAdd(&Sp[avals[0]], acc0);
        if (avals[1] >= 0) atomicAdd(&Sp[avals[1]], acc1);
        if (avals[2] >= 0) atomicAdd(&Sp[avals[2]], acc2);
        if (avals[3] >= 0) atomicAdd(&Sp[avals[3]], acc3);
      }
    }
    __syncthreads();
  }
}

__global__ void k_final(const float* __restrict__ ws, const float* __restrict__ root,
                        float* __restrict__ out, int base31) {
  int b = blockIdx.x, lane = threadIdx.x;
  const float* rmB  = ws + RM_OFF + b*Nn*Nn;
  const float* Sacc = ws + SA_OFF;
  float K = -3.0e38f;
  for (int u = 0; u < 31; ++u)
    K = fmaxf(K, rmB[u] + rmB[(u+1)*Nn + 31]);
  float val = -3.0e38f;
  if (lane < NTn) {
    float sv = Sacc[base31 + b*NTn + lane];
    val = __logf(fmaxf(sv, 1e-38f)) + K + root[b*NTn + lane];
  }
  float m = val;
  for (int d = 32; d >= 1; d >>= 1) m = fmaxf(m, __shfl_xor(m, d, 64));
  float e = (lane < NTn) ? __expf(val - m) : 0.0f;
  for (int d = 32; d >= 1; d >>= 1) e += __shfl_xor(e, d, 64);
  if (lane == 0) out[b] = m + __logf(e);
}

extern "C" void kernel_launch(void* const* d_in, const int* in_sizes, int n_in,
                              void* d_out, int out_size, void* d_ws, size_t ws_size,
                              hipStream_t stream) {
  const float* unary = (const float*)d_in[0];
  const float* rule  = (const float*)d_in[1];
  const float* root  = (const float*)d_in[2];
  float* out = (float*)d_out;
  float* ws  = (float*)d_ws;

  int nrule = 16*30*90*90;
  k_exp<<<dim3((nrule + 255)/256), dim3(256), 0, stream>>>(rule, ws + ER_OFF, nrule);
  k_init<<<dim3((16*32*32*96 + 255)/256), dim3(256), 0, stream>>>(unary, ws);

  int base = 0, basePrev = 0;
  for (int w = 1; w <= 31; ++w) {
    int ns = 32 - w;
    k_step<<<dim3(15, 16), dim3(256), 0, stream>>>(ws, w, base, basePrev);
    basePrev = base;
    base += ns * 16 * 30;
  }
  k_final<<<dim3(16), dim3(64), 0, stream>>>(ws, root, out, basePrev);
}

// Round 3
// 1321.112 us; speedup vs baseline: 1.6143x; 1.6143x over previous
//
#include <hip/hip_runtime.h>
#include <hip/hip_bf16.h>

// PCFG inside algorithm, B=16, n=32, NT=30, T=60, S=90.
// score[b,s,w,a] = log sum_{u,x,c} exp(left[u,x] + right[u,c] + rule[a,x,c])
// computed as  S[a] = sum_{x,c} H[x,c] * er[a,x,c],  H[x,c] = sum_u A'[u,x]*Bv[u,c]
// with A'[u,x] = exp(l + mr_u - K), Bv[u,c] = exp(r - mr_u),
// K = max_u (rowmax(left_u) + rowmax(right_u)); score = log(S) + K.
//
// R2: span loop split across gridDim.z (nsg = min(ns,8), strided spans) to fix
// the measured latency-bound regime (occupancy 6%, VALUBusy 6%).

#define Bn   16
#define Nn   32
#define Tt   60
#define NTn  30
#define Sn   90
#define SPn  96
#define NEGF (-1.0e9f)

// ws layout (floats)
#define ER_OFF   0                         // exp(rule): [16][30][8100]
#define BETA_OFF 3888000                   // beta: [16][32][32][96]
#define RM_OFF   (BETA_OFF + 16*32*32*96)  // rowmax: [16][32][32]
#define SA_OFF   (RM_OFF + 16*32*32)       // S accumulators, per-width regions
#define SA_TOTAL 238080                    // sum_w 16*(32-w)*30

__global__ void k_exp(const float* __restrict__ rule, float* __restrict__ er, int n) {
  int i = blockIdx.x * 256 + threadIdx.x;
  if (i < n) er[i] = __expf(rule[i]);
}

__global__ void k_init(const float* __restrict__ unary, float* __restrict__ ws) {
  int i = blockIdx.x * 256 + threadIdx.x;
  float* beta   = ws + BETA_OFF;
  float* rowmax = ws + RM_OFF;
  float* Sacc   = ws + SA_OFF;
  if (i < 16*32*32*96) {
    int c = i % SPn; int r = i / SPn;
    int j = r % Nn; r /= Nn;
    int ii = r % Nn; int b = r / Nn;
    float v = NEGF;
    if (ii == j && c >= NTn && c < Sn) v = unary[(b*Nn + ii)*Tt + (c - NTn)];
    beta[i] = v;
  }
  if (i < 16*32*32) {
    int j = i % Nn; int r = i / Nn;
    int ii = r % Nn; int b = r / Nn;
    float m = NEGF;
    if (ii == j) {
      const float* u = unary + (b*Nn + ii)*Tt;
      for (int t = 0; t < Tt; ++t) m = fmaxf(m, u[t]);
    }
    rowmax[i] = m;
  }
  if (i < SA_TOTAL) Sacc[i] = 0.0f;
}

__global__ __launch_bounds__(256) void k_step(float* __restrict__ ws, int w,
                                              int baseCur, int basePrev) {
  const int chunk = blockIdx.x;            // 0..14, x-range [6*chunk, 6*chunk+6)
  const int b     = blockIdx.y;            // 0..15
  const int sg    = blockIdx.z;            // span group
  const int nsg   = gridDim.z;
  const int tid   = threadIdx.x;
  const int ns    = Nn - w;
  const int x0    = chunk * 6;
  const int u_lo  = (x0 >= NTn) ? 0 : 1;   // x>=NT only left-diag (u=0); x<NT only u>=1
  const int u_hi  = (x0 >= NTn) ? 1 : w;
  const int nu    = u_hi - u_lo;

  const float* er = ws + ER_OFF;
  float* beta   = ws + BETA_OFF;
  float* rowmax = ws + RM_OFF;
  float* Sacc   = ws + SA_OFF;

  float* betaB = beta + (size_t)b * Nn * Nn * SPn;
  float* rmB   = rowmax + b * Nn * Nn;

  __shared__ float finrow[31][NTn];
  __shared__ float finmax[32];
  __shared__ float KW[32];
  __shared__ float Aa[30][8];
  __shared__ float Bv[30][Sn];
  __shared__ __align__(16) float Hh[540];

  // ---- exp(rule) slice into registers, issued EARLY so the L2/L3 latency
  // overlaps the finalize phase below (er is read-only after k_exp).
  // Thread owns 4 a-values x 5 float4 of k.
  const int g = tid >> 5;   // a-group 0..7
  const int j = tid & 31;   // k-lane 0..31
  float4 ereg[4][5];
  int    avals[4];
  #pragma unroll
  for (int m = 0; m < 4; ++m) {
    int a = g + 8*m;
    avals[m] = (a < NTn) ? a : -1;
    const float4* Ev = (const float4*)(er + ((size_t)b*NTn + (a < NTn ? a : 0))*8100 + x0*Sn);
    #pragma unroll
    for (int i = 0; i < 5; ++i) {
      int f = j + 32*i;
      float4 v = make_float4(0.f, 0.f, 0.f, 0.f);
      if (a < NTn && f < 135) v = Ev[f];
      ereg[m][i] = v;
    }
  }

  // ---- finalize width w-1 rows (redundant per block; bitwise-identical writes) ----
  if (w >= 2) {
    const int wp = w - 1, nsp = Nn - wp;
    if (tid < nsp) {
      float K = -3.0e38f;
      for (int u = 0; u < wp; ++u)
        K = fmaxf(K, rmB[tid*Nn + (tid+u)] + rmB[(tid+u+1)*Nn + (tid+wp)]);
      KW[tid] = K;
    }
    __syncthreads();
    for (int t = tid; t < nsp*NTn; t += 256) {
      int sp = t / NTn, a = t - sp*NTn;
      float sv = Sacc[basePrev + (b*nsp + sp)*NTn + a];
      float sc = __logf(fmaxf(sv, 1e-38f)) + KW[sp];
      finrow[sp][a] = sc;
      betaB[(sp*Nn + (sp+wp))*SPn + a] = sc;
    }
    __syncthreads();
    if (tid < nsp) {
      float m = -3.0e38f;
      for (int a = 0; a < NTn; ++a) m = fmaxf(m, finrow[tid][a]);
      finmax[tid] = m;
      rmB[tid*Nn + (tid+wp)] = m;
    }
    __syncthreads();
  }

  if (nu <= 0) return;   // only happens at w==1 for x<NT chunks (block-uniform)

  // ---- K stabilizers for current width ----
  if (tid < ns) {
    float K = -3.0e38f;
    for (int u = 0; u < w; ++u) {
      float rl = (w >= 2 && u == w-1) ? finmax[tid]   : rmB[tid*Nn + (tid+u)];
      float rr = (w >= 2 && u == 0)   ? finmax[tid+1] : rmB[(tid+u+1)*Nn + (tid+w)];
      K = fmaxf(K, rl + rr);
    }
    KW[tid] = K;
  }
  __syncthreads();

  // ---- span loop (strided across span groups) ----
  for (int s = sg; s < ns; s += nsg) {
    const float K = KW[s];
    // A'[r][xi] = exp(l + mr_u - K)
    for (int t = tid; t < nu*6; t += 256) {
      int r = t / 6, xi = t - r*6;
      int u = u_lo + r;
      int x = x0 + xi;
      float l;
      if (w >= 2 && u == w-1) l = (x < NTn) ? finrow[s][x] : NEGF;
      else                    l = betaB[(s*Nn + (s+u))*SPn + x];
      float rr = (w >= 2 && u == 0) ? finmax[s+1] : rmB[(s+u+1)*Nn + (s+w)];
      Aa[r][xi] = __expf(l + rr - K);
    }
    // Bv[r][c] = exp(r - mr_u)
    for (int t = tid; t < nu*Sn; t += 256) {
      int r = t / Sn, c = t - r*Sn;
      int u = u_lo + r;
      float v;
      if (w >= 2 && u == 0) v = (c < NTn) ? finrow[s+1][c] : NEGF;
      else                  v = betaB[((s+u+1)*Nn + (s+w))*SPn + c];
      float rr = (w >= 2 && u == 0) ? finmax[s+1] : rmB[(s+u+1)*Nn + (s+w)];
      Bv[r][c] = __expf(v - rr);
    }
    __syncthreads();
    // H[x'][c] = sum_u A'*Bv
    for (int t = tid; t < 540; t += 256) {
      int xi = t / Sn, c = t - xi*Sn;
      float acc = 0.f;
      for (int r = 0; r < nu; ++r) acc = fmaf(Aa[r][xi], Bv[r][c], acc);
      Hh[t] = acc;
    }
    __syncthreads();
    // dots: S[a] partial = sum_k H[k]*er[a][k], split-K atomics
    {
      const float4* Hv = (const float4*)Hh;
      float acc0 = 0.f, acc1 = 0.f, acc2 = 0.f, acc3 = 0.f;
      #pragma unroll
      for (int i = 0; i < 5; ++i) {
        int f = j + 32*i;
        if (f < 135) {
          float4 h = Hv[f];
          acc0 += h.x*ereg[0][i].x + h.y*ereg[0][i].y + h.z*ereg[0][i].z + h.w*ereg[0][i].w;
          acc1 += h.x*ereg[1][i].x + h.y*ereg[1][i].y + h.z*ereg[1][i].z + h.w*ereg[1][i].w;
          acc2 += h.x*ereg[2][i].x + h.y*ereg[2][i].y + h.z*ereg[2][i].z + h.w*ereg[2][i].w;
          acc3 += h.x*ereg[3][i].x + h.y*ereg[3][i].y + h.z*ereg[3][i].z + h.w*ereg[3][i].w;
        }
      }
      #pragma unroll
      for (int d = 16; d >= 1; d >>= 1) {
        acc0 += __shfl_down(acc0, d, 32);
        acc1 += __shfl_down(acc1, d, 32);
        acc2 += __shfl_down(acc2, d, 32);
        acc3 += __shfl_down(acc3, d, 32);
      }
      if (j == 0) {
        float* Sp = Sacc + baseCur + (b*ns + s)*NTn;
        if (avals[0] >= 0) atomicAdd(&Sp[avals[0]], acc0);
        if (avals[1] >= 0) atomicAdd(&Sp[avals[1]], acc1);
        if (avals[2] >= 0) atomicAdd(&Sp[avals[2]], acc2);
        if (avals[3] >= 0) atomicAdd(&Sp[avals[3]], acc3);
      }
    }
    __syncthreads();
  }
}

__global__ void k_final(const float* __restrict__ ws, const float* __restrict__ root,
                        float* __restrict__ out, int base31) {
  int b = blockIdx.x, lane = threadIdx.x;
  const float* rmB  = ws + RM_OFF + b*Nn*Nn;
  const float* Sacc = ws + SA_OFF;
  float K = -3.0e38f;
  for (int u = 0; u < 31; ++u)
    K = fmaxf(K, rmB[u] + rmB[(u+1)*Nn + 31]);
  float val = -3.0e38f;
  if (lane < NTn) {
    float sv = Sacc[base31 + b*NTn + lane];
    val = __logf(fmaxf(sv, 1e-38f)) + K + root[b*NTn + lane];
  }
  float m = val;
  for (int d = 32; d >= 1; d >>= 1) m = fmaxf(m, __shfl_xor(m, d, 64));
  float e = (lane < NTn) ? __expf(val - m) : 0.0f;
  for (int d = 32; d >= 1; d >>= 1) e += __shfl_xor(e, d, 64);
  if (lane == 0) out[b] = m + __logf(e);
}

extern "C" void kernel_launch(void* const* d_in, const int* in_sizes, int n_in,
                              void* d_out, int out_size, void* d_ws, size_t ws_size,
                              hipStream_t stream) {
  const float* unary = (const float*)d_in[0];
  const float* rule  = (const float*)d_in[1];
  const float* root  = (const float*)d_in[2];
  float* out = (float*)d_out;
  float* ws  = (float*)d_ws;

  int nrule = 16*30*90*90;
  k_exp<<<dim3((nrule + 255)/256), dim3(256), 0, stream>>>(rule, ws + ER_OFF, nrule);
  k_init<<<dim3((16*32*32*96 + 255)/256), dim3(256), 0, stream>>>(unary, ws);

  int base = 0, basePrev = 0;
  for (int w = 1; w <= 31; ++w) {
    int ns = 32 - w;
    int nsg = ns < 8 ? ns : 8;
    k_step<<<dim3(15, 16, nsg), dim3(256), 0, stream>>>(ws, w, base, basePrev);
    basePrev = base;
    base += ns * 16 * 30;
  }
  k_final<<<dim3(16), dim3(64), 0, stream>>>(ws, root, out, basePrev);
}

// Round 6
// 1117.036 us; speedup vs baseline: 1.9092x; 1.1827x over previous
//
#include <hip/hip_runtime.h>
#include <hip/hip_bf16.h>

// PCFG inside algorithm, B=16, n=32, NT=30, T=60, S=90.
// score[b,s,w,a] = log sum_{u,x,c} exp(left[u,x] + right[u,c] + rule[a,x,c])
// computed as  S[a] = sum_{x,c} H[x,c] * er[a,x,c],  H[x,c] = sum_u A'[u,x]*Bv[u,c]
// with A'[u,x] = exp(l + mr_u - K), Bv[u,c] = exp(r - mr_u),
// K = max_u (rowmax(left_u) + rowmax(right_u)); score = log(S) + K.
//
// R2: span loop split across gridDim.z (latency-bound fix).
// R3: launch_bounds(256,3) to stop the 80-VGPR er-tile spilling to scratch
//     (R2 showed VGPR_Count=68 < 80 needed); dot(s) fused with buildAB(s+nsg)
//     to cut syncs 3->2 per span and hide global latency under FMA work.
// R4/R5: unchanged resubmits (GPU acquisition timeouts; never measured).

#define Bn   16
#define Nn   32
#define Tt   60
#define NTn  30
#define Sn   90
#define SPn  96
#define NEGF (-1.0e9f)

// ws layout (floats)
#define ER_OFF   0                         // exp(rule): [16][30][8100]
#define BETA_OFF 3888000                   // beta: [16][32][32][96]
#define RM_OFF   (BETA_OFF + 16*32*32*96)  // rowmax: [16][32][32]
#define SA_OFF   (RM_OFF + 16*32*32)       // S accumulators, per-width regions
#define SA_TOTAL 238080                    // sum_w 16*(32-w)*30

__global__ void k_exp(const float* __restrict__ rule, float* __restrict__ er, int n) {
  int i = blockIdx.x * 256 + threadIdx.x;
  if (i < n) er[i] = __expf(rule[i]);
}

__global__ void k_init(const float* __restrict__ unary, float* __restrict__ ws) {
  int i = blockIdx.x * 256 + threadIdx.x;
  float* beta   = ws + BETA_OFF;
  float* rowmax = ws + RM_OFF;
  float* Sacc   = ws + SA_OFF;
  if (i < 16*32*32*96) {
    int c = i % SPn; int r = i / SPn;
    int j = r % Nn; r /= Nn;
    int ii = r % Nn; int b = r / Nn;
    float v = NEGF;
    if (ii == j && c >= NTn && c < Sn) v = unary[(b*Nn + ii)*Tt + (c - NTn)];
    beta[i] = v;
  }
  if (i < 16*32*32) {
    int j = i % Nn; int r = i / Nn;
    int ii = r % Nn; int b = r / Nn;
    float m = NEGF;
    if (ii == j) {
      const float* u = unary + (b*Nn + ii)*Tt;
      for (int t = 0; t < Tt; ++t) m = fmaxf(m, u[t]);
    }
    rowmax[i] = m;
  }
  if (i < SA_TOTAL) Sacc[i] = 0.0f;
}

__global__ __launch_bounds__(256, 3) void k_step(float* __restrict__ ws, int w,
                                                 int baseCur, int basePrev) {
  const int chunk = blockIdx.x;            // 0..14, x-range [6*chunk, 6*chunk+6)
  const int b     = blockIdx.y;            // 0..15
  const int sg    = blockIdx.z;            // span group
  const int nsg   = gridDim.z;
  const int tid   = threadIdx.x;
  const int ns    = Nn - w;
  const int x0    = chunk * 6;
  const int u_lo  = (x0 >= NTn) ? 0 : 1;   // x>=NT only left-diag (u=0); x<NT only u>=1
  const int u_hi  = (x0 >= NTn) ? 1 : w;
  const int nu    = u_hi - u_lo;

  const float* er = ws + ER_OFF;
  float* beta   = ws + BETA_OFF;
  float* rowmax = ws + RM_OFF;
  float* Sacc   = ws + SA_OFF;

  float* betaB = beta + (size_t)b * Nn * Nn * SPn;
  float* rmB   = rowmax + b * Nn * Nn;

  __shared__ float finrow[31][NTn];
  __shared__ float finmax[32];
  __shared__ float KW[32];
  __shared__ float Aa[30][8];
  __shared__ float Bv[30][Sn];
  __shared__ __align__(16) float Hh[540];

  // ---- exp(rule) slice into registers, issued EARLY so the L2/L3 latency
  // overlaps the finalize phase below. Thread owns 4 a-values x 5 float4 of k.
  const int g = tid >> 5;   // a-group 0..7
  const int j = tid & 31;   // k-lane 0..31
  float4 ereg[4][5];
  int    avals[4];
  #pragma unroll
  for (int m = 0; m < 4; ++m) {
    int a = g + 8*m;
    avals[m] = (a < NTn) ? a : -1;
    const float4* Ev = (const float4*)(er + ((size_t)b*NTn + (a < NTn ? a : 0))*8100 + x0*Sn);
    #pragma unroll
    for (int i = 0; i < 5; ++i) {
      int f = j + 32*i;
      float4 v = make_float4(0.f, 0.f, 0.f, 0.f);
      if (a < NTn && f < 135) v = Ev[f];
      ereg[m][i] = v;
    }
  }

  // ---- finalize width w-1 rows (redundant per block; bitwise-identical writes) ----
  if (w >= 2) {
    const int wp = w - 1, nsp = Nn - wp;
    if (tid < nsp) {
      float K = -3.0e38f;
      for (int u = 0; u < wp; ++u)
        K = fmaxf(K, rmB[tid*Nn + (tid+u)] + rmB[(tid+u+1)*Nn + (tid+wp)]);
      KW[tid] = K;
    }
    __syncthreads();
    for (int t = tid; t < nsp*NTn; t += 256) {
      int sp = t / NTn, a = t - sp*NTn;
      float sv = Sacc[basePrev + (b*nsp + sp)*NTn + a];
      float sc = __logf(fmaxf(sv, 1e-38f)) + KW[sp];
      finrow[sp][a] = sc;
      betaB[(sp*Nn + (sp+wp))*SPn + a] = sc;
    }
    __syncthreads();
    if (tid < nsp) {
      float m = -3.0e38f;
      for (int a = 0; a < NTn; ++a) m = fmaxf(m, finrow[tid][a]);
      finmax[tid] = m;
      rmB[tid*Nn + (tid+wp)] = m;
    }
    __syncthreads();
  }

  if (nu <= 0) return;   // only happens at w==1 for x<NT chunks (block-uniform)

  // ---- K stabilizers for current width ----
  if (tid < ns) {
    float K = -3.0e38f;
    for (int u = 0; u < w; ++u) {
      float rl = (w >= 2 && u == w-1) ? finmax[tid]   : rmB[tid*Nn + (tid+u)];
      float rr = (w >= 2 && u == 0)   ? finmax[tid+1] : rmB[(tid+u+1)*Nn + (tid+w)];
      K = fmaxf(K, rl + rr);
    }
    KW[tid] = K;
  }
  __syncthreads();

  // ---- phase lambdas ----
  auto buildAB = [&](int s) {
    const float K = KW[s];
    // A'[r][xi] = exp(l + mr_u - K)
    for (int t = tid; t < nu*6; t += 256) {
      int r = t / 6, xi = t - r*6;
      int u = u_lo + r;
      int x = x0 + xi;
      float l;
      if (w >= 2 && u == w-1) l = (x < NTn) ? finrow[s][x] : NEGF;
      else                    l = betaB[(s*Nn + (s+u))*SPn + x];
      float rr = (w >= 2 && u == 0) ? finmax[s+1] : rmB[(s+u+1)*Nn + (s+w)];
      Aa[r][xi] = __expf(l + rr - K);
    }
    // Bv[r][c] = exp(r - mr_u)
    for (int t = tid; t < nu*Sn; t += 256) {
      int r = t / Sn, c = t - r*Sn;
      int u = u_lo + r;
      float v;
      if (w >= 2 && u == 0) v = (c < NTn) ? finrow[s+1][c] : NEGF;
      else                  v = betaB[((s+u+1)*Nn + (s+w))*SPn + c];
      float rr = (w >= 2 && u == 0) ? finmax[s+1] : rmB[(s+u+1)*Nn + (s+w)];
      Bv[r][c] = __expf(v - rr);
    }
  };

  auto buildH = [&]() {
    for (int t = tid; t < 540; t += 256) {
      int xi = t / Sn, c = t - xi*Sn;
      float acc = 0.f;
      for (int r = 0; r < nu; ++r) acc = fmaf(Aa[r][xi], Bv[r][c], acc);
      Hh[t] = acc;
    }
  };

  auto dotPhase = [&](int s) {
    const float4* Hv = (const float4*)Hh;
    float acc0 = 0.f, acc1 = 0.f, acc2 = 0.f, acc3 = 0.f;
    #pragma unroll
    for (int i = 0; i < 5; ++i) {
      int f = j + 32*i;
      if (f < 135) {
        float4 h = Hv[f];
        acc0 += h.x*ereg[0][i].x + h.y*ereg[0][i].y + h.z*ereg[0][i].z + h.w*ereg[0][i].w;
        acc1 += h.x*ereg[1][i].x + h.y*ereg[1][i].y + h.z*ereg[1][i].z + h.w*ereg[1][i].w;
        acc2 += h.x*ereg[2][i].x + h.y*ereg[2][i].y + h.z*ereg[2][i].z + h.w*ereg[2][i].w;
        acc3 += h.x*ereg[3][i].x + h.y*ereg[3][i].y + h.z*ereg[3][i].z + h.w*ereg[3][i].w;
      }
    }
    #pragma unroll
    for (int d = 16; d >= 1; d >>= 1) {
      acc0 += __shfl_down(acc0, d, 32);
      acc1 += __shfl_down(acc1, d, 32);
      acc2 += __shfl_down(acc2, d, 32);
      acc3 += __shfl_down(acc3, d, 32);
    }
    if (j == 0) {
      float* Sp = Sacc + baseCur + (b*ns + s)*NTn;
      if (avals[0] >= 0) atomicAdd(&Sp[avals[0]], acc0);
      if (avals[1] >= 0) atomicAdd(&Sp[avals[1]], acc1);
      if (avals[2] >= 0) atomicAdd(&Sp[avals[2]], acc2);
      if (avals[3] >= 0) atomicAdd(&Sp[avals[3]], acc3);
    }
  };

  // ---- software-pipelined span loop (strided across span groups) ----
  // [AB(s0)] sync [H] sync { [dot(s) + AB(s+nsg)] sync [H] sync }...
  int s = sg;                     // sg < nsg <= ns, so at least one span
  buildAB(s);
  __syncthreads();
  buildH();
  __syncthreads();
  for (;;) {
    int snext = s + nsg;
    bool more = (snext < ns);     // block-uniform
    dotPhase(s);
    if (!more) break;
    buildAB(snext);               // writes Aa/Bv (dead since H); dot reads Hh/ereg only
    __syncthreads();
    buildH();
    __syncthreads();
    s = snext;
  }
}

__global__ void k_final(const float* __restrict__ ws, const float* __restrict__ root,
                        float* __restrict__ out, int base31) {
  int b = blockIdx.x, lane = threadIdx.x;
  const float* rmB  = ws + RM_OFF + b*Nn*Nn;
  const float* Sacc = ws + SA_OFF;
  float K = -3.0e38f;
  for (int u = 0; u < 31; ++u)
    K = fmaxf(K, rmB[u] + rmB[(u+1)*Nn + 31]);
  float val = -3.0e38f;
  if (lane < NTn) {
    float sv = Sacc[base31 + b*NTn + lane];
    val = __logf(fmaxf(sv, 1e-38f)) + K + root[b*NTn + lane];
  }
  float m = val;
  for (int d = 32; d >= 1; d >>= 1) m = fmaxf(m, __shfl_xor(m, d, 64));
  float e = (lane < NTn) ? __expf(val - m) : 0.0f;
  for (int d = 32; d >= 1; d >>= 1) e += __shfl_xor(e, d, 64);
  if (lane == 0) out[b] = m + __logf(e);
}

extern "C" void kernel_launch(void* const* d_in, const int* in_sizes, int n_in,
                              void* d_out, int out_size, void* d_ws, size_t ws_size,
                              hipStream_t stream) {
  const float* unary = (const float*)d_in[0];
  const float* rule  = (const float*)d_in[1];
  const float* root  = (const float*)d_in[2];
  float* out = (float*)d_out;
  float* ws  = (float*)d_ws;

  int nrule = 16*30*90*90;
  k_exp<<<dim3((nrule + 255)/256), dim3(256), 0, stream>>>(rule, ws + ER_OFF, nrule);
  k_init<<<dim3((16*32*32*96 + 255)/256), dim3(256), 0, stream>>>(unary, ws);

  int base = 0, basePrev = 0;
  for (int w = 1; w <= 31; ++w) {
    int ns = 32 - w;
    int nsg = ns < 8 ? ns : 8;
    k_step<<<dim3(15, 16, nsg), dim3(256), 0, stream>>>(ws, w, base, basePrev);
    basePrev = base;
    base += ns * 16 * 30;
  }
  k_final<<<dim3(16), dim3(64), 0, stream>>>(ws, root, out, basePrev);
}

// Round 7
// 1025.098 us; speedup vs baseline: 2.0804x; 1.0897x over previous
//
#include <hip/hip_runtime.h>
#include <hip/hip_bf16.h>

// PCFG inside algorithm, B=16, n=32, NT=30, T=60, S=90.
// score[b,s,w,a] = log sum_{u,x,c} exp(left[u,x] + right[u,c] + rule[a,x,c])
// computed as  S[a] = sum_{x,c} H[x,c] * er[a,x,c],  H[x,c] = sum_u A'[u,x]*Bv[u,c]
// with A'[u,x] = exp(l + mr_u - K), Bv[u,c] = exp(r - mr_u),
// K = max_u (rowmax(left_u) + rowmax(right_u)); score = log(S) + K.
//
// R2: span loop split across gridDim.z (latency-bound fix).
// R3: launch_bounds(256,3) + pipelined dot(s)/buildAB(s+nsg).  (VGPR theory was
//     wrong - compiler holds ereg in AGPRs; win came from pipelining.)
// R6: rmB staged to LDS (4KB) once per block - kills the per-thread serial
//     u-loops of dependent ~400cy global loads (finalize-K, stabilizer-K,
//     buildAB rr) that dominated the width-flat ~50us step time.

#define Bn   16
#define Nn   32
#define Tt   60
#define NTn  30
#define Sn   90
#define SPn  96
#define NEGF (-1.0e9f)

// ws layout (floats)
#define ER_OFF   0                         // exp(rule): [16][30][8100]
#define BETA_OFF 3888000                   // beta: [16][32][32][96]
#define RM_OFF   (BETA_OFF + 16*32*32*96)  // rowmax: [16][32][32]
#define SA_OFF   (RM_OFF + 16*32*32)       // S accumulators, per-width regions
#define SA_TOTAL 238080                    // sum_w 16*(32-w)*30

__global__ void k_exp(const float* __restrict__ rule, float* __restrict__ er, int n) {
  int i = blockIdx.x * 256 + threadIdx.x;
  if (i < n) er[i] = __expf(rule[i]);
}

__global__ void k_init(const float* __restrict__ unary, float* __restrict__ ws) {
  int i = blockIdx.x * 256 + threadIdx.x;
  float* beta   = ws + BETA_OFF;
  float* rowmax = ws + RM_OFF;
  float* Sacc   = ws + SA_OFF;
  if (i < 16*32*32*96) {
    int c = i % SPn; int r = i / SPn;
    int j = r % Nn; r /= Nn;
    int ii = r % Nn; int b = r / Nn;
    float v = NEGF;
    if (ii == j && c >= NTn && c < Sn) v = unary[(b*Nn + ii)*Tt + (c - NTn)];
    beta[i] = v;
  }
  if (i < 16*32*32) {
    int j = i % Nn; int r = i / Nn;
    int ii = r % Nn; int b = r / Nn;
    float m = NEGF;
    if (ii == j) {
      const float* u = unary + (b*Nn + ii)*Tt;
      for (int t = 0; t < Tt; ++t) m = fmaxf(m, u[t]);
    }
    rowmax[i] = m;
  }
  if (i < SA_TOTAL) Sacc[i] = 0.0f;
}

__global__ __launch_bounds__(256, 3) void k_step(float* __restrict__ ws, int w,
                                                 int baseCur, int basePrev) {
  const int chunk = blockIdx.x;            // 0..14, x-range [6*chunk, 6*chunk+6)
  const int b     = blockIdx.y;            // 0..15
  const int sg    = blockIdx.z;            // span group
  const int nsg   = gridDim.z;
  const int tid   = threadIdx.x;
  const int ns    = Nn - w;
  const int x0    = chunk * 6;
  const int u_lo  = (x0 >= NTn) ? 0 : 1;   // x>=NT only left-diag (u=0); x<NT only u>=1
  const int u_hi  = (x0 >= NTn) ? 1 : w;
  const int nu    = u_hi - u_lo;

  const float* er = ws + ER_OFF;
  float* beta   = ws + BETA_OFF;
  float* rowmax = ws + RM_OFF;
  float* Sacc   = ws + SA_OFF;

  float* betaB = beta + (size_t)b * Nn * Nn * SPn;
  float* rmB   = rowmax + b * Nn * Nn;

  __shared__ float finrow[31][NTn];
  __shared__ float finmax[32];
  __shared__ float KW[32];
  __shared__ float rmLds[Nn][Nn];          // R6: rowmax cache, [row][col], stride-33 reads
  __shared__ float Aa[30][8];
  __shared__ float Bv[30][Sn];
  __shared__ __align__(16) float Hh[540];

  // ---- exp(rule) slice into registers, issued EARLY (L2/L3 latency overlaps
  // the staging + finalize below). Thread owns 4 a-values x 5 float4 of k.
  const int g = tid >> 5;   // a-group 0..7
  const int j = tid & 31;   // k-lane 0..31
  float4 ereg[4][5];
  int    avals[4];
  #pragma unroll
  for (int m = 0; m < 4; ++m) {
    int a = g + 8*m;
    avals[m] = (a < NTn) ? a : -1;
    const float4* Ev = (const float4*)(er + ((size_t)b*NTn + (a < NTn ? a : 0))*8100 + x0*Sn);
    #pragma unroll
    for (int i = 0; i < 5; ++i) {
      int f = j + 32*i;
      float4 v = make_float4(0.f, 0.f, 0.f, 0.f);
      if (a < NTn && f < 135) v = Ev[f];
      ereg[m][i] = v;
    }
  }

  // ---- R6: stage rowmax into LDS (coalesced; valid for widths <= w-2 here;
  // the width w-1 entries are filled by finalize below) ----
  {
    float* rl = &rmLds[0][0];
    #pragma unroll
    for (int t = 0; t < 4; ++t) rl[tid + 256*t] = rmB[tid + 256*t];
  }
  __syncthreads();

  // ---- finalize width w-1 rows (redundant per block; bitwise-identical writes) ----
  if (w >= 2) {
    const int wp = w - 1, nsp = Nn - wp;
    if (tid < nsp) {
      float K = -3.0e38f;
      for (int u = 0; u < wp; ++u)
        K = fmaxf(K, rmLds[tid][tid+u] + rmLds[tid+u+1][tid+wp]);
      KW[tid] = K;
    }
    __syncthreads();
    for (int t = tid; t < nsp*NTn; t += 256) {
      int sp = t / NTn, a = t - sp*NTn;
      float sv = Sacc[basePrev + (b*nsp + sp)*NTn + a];
      float sc = __logf(fmaxf(sv, 1e-38f)) + KW[sp];
      finrow[sp][a] = sc;
      betaB[(sp*Nn + (sp+wp))*SPn + a] = sc;
    }
    __syncthreads();
    if (tid < nsp) {
      float m = -3.0e38f;
      for (int a = 0; a < NTn; ++a) m = fmaxf(m, finrow[tid][a]);
      finmax[tid] = m;
      rmLds[tid][tid+wp] = m;              // LDS copy for this kernel
      rmB[tid*Nn + (tid+wp)] = m;          // global copy for later launches
    }
    __syncthreads();
  }

  if (nu <= 0) return;   // only happens at w==1 for x<NT chunks (block-uniform)

  // ---- K stabilizers for current width (all reads from LDS now) ----
  if (tid < ns) {
    float K = -3.0e38f;
    for (int u = 0; u < w; ++u) {
      float rl = (w >= 2 && u == w-1) ? finmax[tid]   : rmLds[tid][tid+u];
      float rr = (w >= 2 && u == 0)   ? finmax[tid+1] : rmLds[tid+u+1][tid+w];
      K = fmaxf(K, rl + rr);
    }
    KW[tid] = K;
  }
  __syncthreads();

  // ---- phase lambdas ----
  auto buildAB = [&](int s) {
    const float K = KW[s];
    // A'[r][xi] = exp(l + mr_u - K)
    for (int t = tid; t < nu*6; t += 256) {
      int r = t / 6, xi = t - r*6;
      int u = u_lo + r;
      int x = x0 + xi;
      float l;
      if (w >= 2 && u == w-1) l = (x < NTn) ? finrow[s][x] : NEGF;
      else                    l = betaB[(s*Nn + (s+u))*SPn + x];
      float rr = (w >= 2 && u == 0) ? finmax[s+1] : rmLds[s+u+1][s+w];
      Aa[r][xi] = __expf(l + rr - K);
    }
    // Bv[r][c] = exp(r - mr_u)
    for (int t = tid; t < nu*Sn; t += 256) {
      int r = t / Sn, c = t - r*Sn;
      int u = u_lo + r;
      float v;
      if (w >= 2 && u == 0) v = (c < NTn) ? finrow[s+1][c] : NEGF;
      else                  v = betaB[((s+u+1)*Nn + (s+w))*SPn + c];
      float rr = (w >= 2 && u == 0) ? finmax[s+1] : rmLds[s+u+1][s+w];
      Bv[r][c] = __expf(v - rr);
    }
  };

  auto buildH = [&]() {
    for (int t = tid; t < 540; t += 256) {
      int xi = t / Sn, c = t - xi*Sn;
      float acc = 0.f;
      for (int r = 0; r < nu; ++r) acc = fmaf(Aa[r][xi], Bv[r][c], acc);
      Hh[t] = acc;
    }
  };

  auto dotPhase = [&](int s) {
    const float4* Hv = (const float4*)Hh;
    float acc0 = 0.f, acc1 = 0.f, acc2 = 0.f, acc3 = 0.f;
    #pragma unroll
    for (int i = 0; i < 5; ++i) {
      int f = j + 32*i;
      if (f < 135) {
        float4 h = Hv[f];
        acc0 += h.x*ereg[0][i].x + h.y*ereg[0][i].y + h.z*ereg[0][i].z + h.w*ereg[0][i].w;
        acc1 += h.x*ereg[1][i].x + h.y*ereg[1][i].y + h.z*ereg[1][i].z + h.w*ereg[1][i].w;
        acc2 += h.x*ereg[2][i].x + h.y*ereg[2][i].y + h.z*ereg[2][i].z + h.w*ereg[2][i].w;
        acc3 += h.x*ereg[3][i].x + h.y*ereg[3][i].y + h.z*ereg[3][i].z + h.w*ereg[3][i].w;
      }
    }
    #pragma unroll
    for (int d = 16; d >= 1; d >>= 1) {
      acc0 += __shfl_down(acc0, d, 32);
      acc1 += __shfl_down(acc1, d, 32);
      acc2 += __shfl_down(acc2, d, 32);
      acc3 += __shfl_down(acc3, d, 32);
    }
    if (j == 0) {
      float* Sp = Sacc + baseCur + (b*ns + s)*NTn;
      if (avals[0] >= 0) atomicAdd(&Sp[avals[0]], acc0);
      if (avals[1] >= 0) atomicAdd(&Sp[avals[1]], acc1);
      if (avals[2] >= 0) atomicAdd(&Sp[avals[2]], acc2);
      if (avals[3] >= 0) atomicAdd(&Sp[avals[3]], acc3);
    }
  };

  // ---- software-pipelined span loop (strided across span groups) ----
  // [AB(s0)] sync [H] sync { [dot(s) + AB(s+nsg)] sync [H] sync }...
  int s = sg;                     // sg < nsg <= ns, so at least one span
  buildAB(s);
  __syncthreads();
  buildH();
  __syncthreads();
  for (;;) {
    int snext = s + nsg;
    bool more = (snext < ns);     // block-uniform
    dotPhase(s);
    if (!more) break;
    buildAB(snext);               // writes Aa/Bv (dead since H); dot reads Hh/ereg only
    __syncthreads();
    buildH();
    __syncthreads();
    s = snext;
  }
}

__global__ void k_final(const float* __restrict__ ws, const float* __restrict__ root,
                        float* __restrict__ out, int base31) {
  int b = blockIdx.x, lane = threadIdx.x;
  const float* rmB  = ws + RM_OFF + b*Nn*Nn;
  const float* Sacc = ws + SA_OFF;
  float K = -3.0e38f;
  for (int u = 0; u < 31; ++u)
    K = fmaxf(K, rmB[u] + rmB[(u+1)*Nn + 31]);
  float val = -3.0e38f;
  if (lane < NTn) {
    float sv = Sacc[base31 + b*NTn + lane];
    val = __logf(fmaxf(sv, 1e-38f)) + K + root[b*NTn + lane];
  }
  float m = val;
  for (int d = 32; d >= 1; d >>= 1) m = fmaxf(m, __shfl_xor(m, d, 64));
  float e = (lane < NTn) ? __expf(val - m) : 0.0f;
  for (int d = 32; d >= 1; d >>= 1) e += __shfl_xor(e, d, 64);
  if (lane == 0) out[b] = m + __logf(e);
}

extern "C" void kernel_launch(void* const* d_in, const int* in_sizes, int n_in,
                              void* d_out, int out_size, void* d_ws, size_t ws_size,
                              hipStream_t stream) {
  const float* unary = (const float*)d_in[0];
  const float* rule  = (const float*)d_in[1];
  const float* root  = (const float*)d_in[2];
  float* out = (float*)d_out;
  float* ws  = (float*)d_ws;

  int nrule = 16*30*90*90;
  k_exp<<<dim3((nrule + 255)/256), dim3(256), 0, stream>>>(rule, ws + ER_OFF, nrule);
  k_init<<<dim3((16*32*32*96 + 255)/256), dim3(256), 0, stream>>>(unary, ws);

  int base = 0, basePrev = 0;
  for (int w = 1; w <= 31; ++w) {
    int ns = 32 - w;
    int nsg = ns < 8 ? ns : 8;
    k_step<<<dim3(15, 16, nsg), dim3(256), 0, stream>>>(ws, w, base, basePrev);
    basePrev = base;
    base += ns * 16 * 30;
  }
  k_final<<<dim3(16), dim3(64), 0, stream>>>(ws, root, out, basePrev);
}

// Round 11
// 830.078 us; speedup vs baseline: 2.5692x; 1.2349x over previous
//
#include <hip/hip_runtime.h>
#include <hip/hip_bf16.h>

// PCFG inside algorithm, B=16, n=32, NT=30, T=60, S=90.
// score[b,s,w,a] = log sum_{u,x,c} exp(left[u,x] + right[u,c] + rule[a,x,c])
// computed as  S[a] = sum_{x,c} H[x,c] * er[a,x,c],  H[x,c] = sum_u A'[u,x]*Bv[u,c]
// with A'[u,x] = exp(l + mr_u - K), Bv[u,c] = exp(r - mr_u),
// K = max_u (rowmax(left_u) + rowmax(right_u)); score = log(S) + K.
//
// R2: span loop split across gridDim.z (latency-bound fix).
// R3: pipelined dot(s)/buildAB(s+nsg).
// R6: rmB staged to LDS (kills serial dependent-global u-loops).
// R7: single-occupancy-round step: ereg remapped to 16-lane groups
//     (2 a x 9 float4 = 72 AGPR, was 80), launch_bounds(256,4) -> 4 blocks/CU,
//     nsg 8->4 so grid (<=960) fits one concurrent wave of blocks.
// R8-R10: unchanged resubmits (GPU acquisition timeouts; R7 never measured).

#define Bn   16
#define Nn   32
#define Tt   60
#define NTn  30
#define Sn   90
#define SPn  96
#define NEGF (-1.0e9f)

// ws layout (floats)
#define ER_OFF   0                         // exp(rule): [16][30][8100]
#define BETA_OFF 3888000                   // beta: [16][32][32][96]
#define RM_OFF   (BETA_OFF + 16*32*32*96)  // rowmax: [16][32][32]
#define SA_OFF   (RM_OFF + 16*32*32)       // S accumulators, per-width regions
#define SA_TOTAL 238080                    // sum_w 16*(32-w)*30

__global__ void k_exp(const float* __restrict__ rule, float* __restrict__ er, int n) {
  int i = blockIdx.x * 256 + threadIdx.x;
  if (i < n) er[i] = __expf(rule[i]);
}

__global__ void k_init(const float* __restrict__ unary, float* __restrict__ ws) {
  int i = blockIdx.x * 256 + threadIdx.x;
  float* beta   = ws + BETA_OFF;
  float* rowmax = ws + RM_OFF;
  float* Sacc   = ws + SA_OFF;
  if (i < 16*32*32*96) {
    int c = i % SPn; int r = i / SPn;
    int j = r % Nn; r /= Nn;
    int ii = r % Nn; int b = r / Nn;
    float v = NEGF;
    if (ii == j && c >= NTn && c < Sn) v = unary[(b*Nn + ii)*Tt + (c - NTn)];
    beta[i] = v;
  }
  if (i < 16*32*32) {
    int j = i % Nn; int r = i / Nn;
    int ii = r % Nn; int b = r / Nn;
    float m = NEGF;
    if (ii == j) {
      const float* u = unary + (b*Nn + ii)*Tt;
      for (int t = 0; t < Tt; ++t) m = fmaxf(m, u[t]);
    }
    rowmax[i] = m;
  }
  if (i < SA_TOTAL) Sacc[i] = 0.0f;
}

__global__ __launch_bounds__(256, 4) void k_step(float* __restrict__ ws, int w,
                                                 int baseCur, int basePrev) {
  const int chunk = blockIdx.x;            // 0..14, x-range [6*chunk, 6*chunk+6)
  const int b     = blockIdx.y;            // 0..15
  const int sg    = blockIdx.z;            // span group
  const int nsg   = gridDim.z;
  const int tid   = threadIdx.x;
  const int ns    = Nn - w;
  const int x0    = chunk * 6;
  const int u_lo  = (x0 >= NTn) ? 0 : 1;   // x>=NT only left-diag (u=0); x<NT only u>=1
  const int u_hi  = (x0 >= NTn) ? 1 : w;
  const int nu    = u_hi - u_lo;

  const float* er = ws + ER_OFF;
  float* beta   = ws + BETA_OFF;
  float* rowmax = ws + RM_OFF;
  float* Sacc   = ws + SA_OFF;

  float* betaB = beta + (size_t)b * Nn * Nn * SPn;
  float* rmB   = rowmax + b * Nn * Nn;

  __shared__ float finrow[31][NTn];
  __shared__ float finmax[32];
  __shared__ float KW[32];
  __shared__ float rmLds[Nn][Nn];          // rowmax cache
  __shared__ float Aa[30][8];
  __shared__ float Bv[30][Sn];
  __shared__ __align__(16) float Hh[540];

  // ---- exp(rule) slice into registers, issued EARLY (latency overlaps the
  // staging + finalize below). R7 mapping: 16 groups of 16 lanes; thread owns
  // 2 a-values x 9 float4 of k (72 regs, was 80).
  const int g = tid >> 4;   // a-group 0..15
  const int j = tid & 15;   // k-lane 0..15
  float4 ereg[2][9];
  int    avals[2];
  avals[0] = g;                            // g <= 15 < NT, always valid
  avals[1] = (g + 16 < NTn) ? g + 16 : -1;
  #pragma unroll
  for (int m = 0; m < 2; ++m) {
    int a = (avals[m] >= 0) ? avals[m] : 0;
    const float4* Ev = (const float4*)(er + ((size_t)b*NTn + a)*8100 + x0*Sn);
    #pragma unroll
    for (int i = 0; i < 9; ++i) {
      int f = j + 16*i;
      float4 v = make_float4(0.f, 0.f, 0.f, 0.f);
      if (avals[m] >= 0 && f < 135) v = Ev[f];
      ereg[m][i] = v;
    }
  }

  // ---- stage rowmax into LDS (coalesced; width w-1 entries filled by finalize) ----
  {
    float* rl = &rmLds[0][0];
    #pragma unroll
    for (int t = 0; t < 4; ++t) rl[tid + 256*t] = rmB[tid + 256*t];
  }
  __syncthreads();

  // ---- finalize width w-1 rows (redundant per block; bitwise-identical writes) ----
  if (w >= 2) {
    const int wp = w - 1, nsp = Nn - wp;
    if (tid < nsp) {
      float K = -3.0e38f;
      for (int u = 0; u < wp; ++u)
        K = fmaxf(K, rmLds[tid][tid+u] + rmLds[tid+u+1][tid+wp]);
      KW[tid] = K;
    }
    __syncthreads();
    for (int t = tid; t < nsp*NTn; t += 256) {
      int sp = t / NTn, a = t - sp*NTn;
      float sv = Sacc[basePrev + (b*nsp + sp)*NTn + a];
      float sc = __logf(fmaxf(sv, 1e-38f)) + KW[sp];
      finrow[sp][a] = sc;
      betaB[(sp*Nn + (sp+wp))*SPn + a] = sc;
    }
    __syncthreads();
    if (tid < nsp) {
      float m = -3.0e38f;
      for (int a = 0; a < NTn; ++a) m = fmaxf(m, finrow[tid][a]);
      finmax[tid] = m;
      rmLds[tid][tid+wp] = m;              // LDS copy for this kernel
      rmB[tid*Nn + (tid+wp)] = m;          // global copy for later launches
    }
    __syncthreads();
  }

  if (nu <= 0) return;   // only happens at w==1 for x<NT chunks (block-uniform)

  // ---- K stabilizers for current width (LDS reads) ----
  if (tid < ns) {
    float K = -3.0e38f;
    for (int u = 0; u < w; ++u) {
      float rl = (w >= 2 && u == w-1) ? finmax[tid]   : rmLds[tid][tid+u];
      float rr = (w >= 2 && u == 0)   ? finmax[tid+1] : rmLds[tid+u+1][tid+w];
      K = fmaxf(K, rl + rr);
    }
    KW[tid] = K;
  }
  __syncthreads();

  // ---- phase lambdas ----
  auto buildAB = [&](int s) {
    const float K = KW[s];
    // A'[r][xi] = exp(l + mr_u - K)
    for (int t = tid; t < nu*6; t += 256) {
      int r = t / 6, xi = t - r*6;
      int u = u_lo + r;
      int x = x0 + xi;
      float l;
      if (w >= 2 && u == w-1) l = (x < NTn) ? finrow[s][x] : NEGF;
      else                    l = betaB[(s*Nn + (s+u))*SPn + x];
      float rr = (w >= 2 && u == 0) ? finmax[s+1] : rmLds[s+u+1][s+w];
      Aa[r][xi] = __expf(l + rr - K);
    }
    // Bv[r][c] = exp(r - mr_u)
    for (int t = tid; t < nu*Sn; t += 256) {
      int r = t / Sn, c = t - r*Sn;
      int u = u_lo + r;
      float v;
      if (w >= 2 && u == 0) v = (c < NTn) ? finrow[s+1][c] : NEGF;
      else                  v = betaB[((s+u+1)*Nn + (s+w))*SPn + c];
      float rr = (w >= 2 && u == 0) ? finmax[s+1] : rmLds[s+u+1][s+w];
      Bv[r][c] = __expf(v - rr);
    }
  };

  auto buildH = [&]() {
    for (int t = tid; t < 540; t += 256) {
      int xi = t / Sn, c = t - xi*Sn;
      float acc = 0.f;
      for (int r = 0; r < nu; ++r) acc = fmaf(Aa[r][xi], Bv[r][c], acc);
      Hh[t] = acc;
    }
  };

  auto dotPhase = [&](int s) {
    const float4* Hv = (const float4*)Hh;
    float acc0 = 0.f, acc1 = 0.f;
    #pragma unroll
    for (int i = 0; i < 9; ++i) {
      int f = j + 16*i;
      if (f < 135) {
        float4 h = Hv[f];
        acc0 += h.x*ereg[0][i].x + h.y*ereg[0][i].y + h.z*ereg[0][i].z + h.w*ereg[0][i].w;
        acc1 += h.x*ereg[1][i].x + h.y*ereg[1][i].y + h.z*ereg[1][i].z + h.w*ereg[1][i].w;
      }
    }
    #pragma unroll
    for (int d = 8; d >= 1; d >>= 1) {
      acc0 += __shfl_down(acc0, d, 16);
      acc1 += __shfl_down(acc1, d, 16);
    }
    if (j == 0) {
      float* Sp = Sacc + baseCur + (b*ns + s)*NTn;
      atomicAdd(&Sp[avals[0]], acc0);
      if (avals[1] >= 0) atomicAdd(&Sp[avals[1]], acc1);
    }
  };

  // ---- software-pipelined span loop (strided across span groups) ----
  // [AB(s0)] sync [H] sync { [dot(s) + AB(s+nsg)] sync [H] sync }...
  int s = sg;                     // sg < nsg <= ns, so at least one span
  buildAB(s);
  __syncthreads();
  buildH();
  __syncthreads();
  for (;;) {
    int snext = s + nsg;
    bool more = (snext < ns);     // block-uniform
    dotPhase(s);
    if (!more) break;
    buildAB(snext);               // writes Aa/Bv (dead since H); dot reads Hh/ereg only
    __syncthreads();
    buildH();
    __syncthreads();
    s = snext;
  }
}

__global__ void k_final(const float* __restrict__ ws, const float* __restrict__ root,
                        float* __restrict__ out, int base31) {
  int b = blockIdx.x, lane = threadIdx.x;
  const float* rmB  = ws + RM_OFF + b*Nn*Nn;
  const float* Sacc = ws + SA_OFF;
  float K = -3.0e38f;
  for (int u = 0; u < 31; ++u)
    K = fmaxf(K, rmB[u] + rmB[(u+1)*Nn + 31]);
  float val = -3.0e38f;
  if (lane < NTn) {
    float sv = Sacc[base31 + b*NTn + lane];
    val = __logf(fmaxf(sv, 1e-38f)) + K + root[b*NTn + lane];
  }
  float m = val;
  for (int d = 32; d >= 1; d >>= 1) m = fmaxf(m, __shfl_xor(m, d, 64));
  float e = (lane < NTn) ? __expf(val - m) : 0.0f;
  for (int d = 32; d >= 1; d >>= 1) e += __shfl_xor(e, d, 64);
  if (lane == 0) out[b] = m + __logf(e);
}

extern "C" void kernel_launch(void* const* d_in, const int* in_sizes, int n_in,
                              void* d_out, int out_size, void* d_ws, size_t ws_size,
                              hipStream_t stream) {
  const float* unary = (const float*)d_in[0];
  const float* rule  = (const float*)d_in[1];
  const float* root  = (const float*)d_in[2];
  float* out = (float*)d_out;
  float* ws  = (float*)d_ws;

  int nrule = 16*30*90*90;
  k_exp<<<dim3((nrule + 255)/256), dim3(256), 0, stream>>>(rule, ws + ER_OFF, nrule);
  k_init<<<dim3((16*32*32*96 + 255)/256), dim3(256), 0, stream>>>(unary, ws);

  int base = 0, basePrev = 0;
  for (int w = 1; w <= 31; ++w) {
    int ns = 32 - w;
    int nsg = ns < 4 ? ns : 4;
    k_step<<<dim3(15, 16, nsg), dim3(256), 0, stream>>>(ws, w, base, basePrev);
    basePrev = base;
    base += ns * 16 * 30;
  }
  k_final<<<dim3(16), dim3(64), 0, stream>>>(ws, root, out, basePrev);
}